// Round 12
// baseline (790.881 us; speedup 1.0000x reference)
//
#include <hip/hip_runtime.h>
#include <math.h>

#define BB 64
#define TT 2048
#define FF 128
#define HH 32
#define GG 128  // 4*H

// gate-column prescale: sigma(a) = rcp(1 + exp2(S1*a)), tanh(a) = 2*rcp(1+exp2(S2*a))-1
#define S1f (-1.4426950408889634f)  // -log2(e)
#define S2f (-2.8853900817779268f)  // -2*log2(e)

typedef _Float16 half2_t __attribute__((ext_vector_type(2)));

__device__ __forceinline__ unsigned h2u(half2_t v) {
    unsigned u; __builtin_memcpy(&u, &v, 4); return u;
}
__device__ __forceinline__ half2_t u2h(unsigned u) {
    half2_t v; __builtin_memcpy(&v, &u, 4); return v;
}
__device__ __forceinline__ half2_t pkrtz(float a, float b) {
    auto r = __builtin_amdgcn_cvt_pkrtz(a, b);  // __fp16 vec2, same bits
    half2_t v; __builtin_memcpy(&v, &r, 4); return v;
}
__device__ __forceinline__ float rcp_(float x) { return __builtin_amdgcn_rcpf(x); }
__device__ __forceinline__ float exp2_(float x) { return __builtin_amdgcn_exp2f(x); }
__device__ __forceinline__ float fdot2_(half2_t a, half2_t b, float c) {
    return __builtin_amdgcn_fdot2(a, b, c, false);
}

// DPP lane shuffles (within rows of 16 / quads); bound_ctrl=1, all rows/banks
#define DPP_(x, ctrl) \
    ((unsigned)__builtin_amdgcn_mov_dpp((int)(x), (ctrl), 0xF, 0xF, true))
#define CTRL_XOR1 0xB1  // quad_perm [1,0,3,2]
#define CTRL_XOR2 0x4E  // quad_perm [2,3,0,1]
#define CTRL_ROR4 0x124 // row_ror:4
#define CTRL_ROR8 0x128 // row_ror:8
// ds_swizzle bit-mode xor16 within 32-lane groups: (16<<10)|0x1F
#define SWZ16_(x) ((unsigned)__builtin_amdgcn_ds_swizzle((int)(x), 0x401F))

#if __has_builtin(__builtin_amdgcn_permlane16_swap)
#define HAVE_PL16 1
#else
#define HAVE_PL16 0
#endif

// Reference tree (used for the setup-time index discovery; the dual-step
// below replicates this op sequence exactly, statement-interleaved).
__device__ __forceinline__ void gather_tree(unsigned v0, unsigned g[16]) {
    unsigned v1 = DPP_(v0, CTRL_XOR2);
#if HAVE_PL16
    auto sw = __builtin_amdgcn_permlane16_swap(v0, v1, false, false);
    unsigned s0 = (unsigned)sw[0], s1 = (unsigned)sw[1];
    g[0] = s0;
    g[1] = s1;
    g[2] = DPP_(s0, CTRL_XOR2);
    g[3] = DPP_(s1, CTRL_XOR2);
#else
    g[0] = v0;
    g[1] = v1;
    g[2] = SWZ16_(v0);
    g[3] = SWZ16_(v1);
#endif
#pragma unroll
    for (int r = 0; r < 4; ++r) g[4 + r] = DPP_(g[r], CTRL_ROR4);
#pragma unroll
    for (int r = 0; r < 8; ++r) g[8 + r] = DPP_(g[r], CTRL_ROR8);
}

// ---- Kernel 1: xg2[b][j][t] = half2( S*(X@Wx+b)[col j], S*(X@Wx+b)[col j+64] )
// packed fp16 pairs, [64 cols][2048 t] per batch, 4B per (j,t).
__global__ __launch_bounds__(256) void xg_gemm(const float* __restrict__ X,
                                               const float* __restrict__ Wx,
                                               const float* __restrict__ bias,
                                               unsigned* __restrict__ xg2) {
    __shared__ float XL[64 * 32];    // [row][fi]  8 KB
    __shared__ float WL[32 * 128];   // [fi][col] 16 KB
    const int tid = threadIdx.x;
    const int row0 = blockIdx.x * 64;   // flattened b*T + t0 (one b per block)
    const int j0 = (tid & 15) * 4;   // 4 X-cols (j0..j0+3) + 4 Y-cols (+64)
    const int r0 = (tid >> 4) * 4;   // 4 output rows (consecutive t)

    float acc[4][8];                 // [row][4 X + 4 Y]
#pragma unroll
    for (int r = 0; r < 4; ++r)
#pragma unroll
        for (int jj = 0; jj < 8; ++jj) acc[r][jj] = 0.f;

    for (int f0 = 0; f0 < FF; f0 += 32) {
        __syncthreads();
        {
            const float4* src = (const float4*)(Wx + f0 * GG);
            float4* dst = (float4*)WL;
            dst[tid]       = src[tid];
            dst[tid + 256] = src[tid + 256];
            dst[tid + 512] = src[tid + 512];
            dst[tid + 768] = src[tid + 768];
        }
        {
            int lin = tid * 4;
            int row = lin >> 5;
            int fi  = lin & 31;
            ((float4*)XL)[tid] =
                *(const float4*)(X + (size_t)(row0 + row) * FF + f0 + fi);
            lin = (tid + 256) * 4;
            row = lin >> 5;
            fi  = lin & 31;
            ((float4*)XL)[tid + 256] =
                *(const float4*)(X + (size_t)(row0 + row) * FF + f0 + fi);
        }
        __syncthreads();
#pragma unroll 4
        for (int fi = 0; fi < 32; ++fi) {
            float xv[4];
#pragma unroll
            for (int r = 0; r < 4; ++r) xv[r] = XL[(r0 + r) * 32 + fi];
            float4 w0 = *(float4*)&WL[fi * GG + j0];        // X cols
            float4 w1 = *(float4*)&WL[fi * GG + j0 + 64];   // Y cols
            float w[8] = {w0.x, w0.y, w0.z, w0.w, w1.x, w1.y, w1.z, w1.w};
#pragma unroll
            for (int r = 0; r < 4; ++r)
#pragma unroll
                for (int jj = 0; jj < 8; ++jj)
                    acc[r][jj] = fmaf(xv[r], w[jj], acc[r][jj]);
        }
    }
    const int b  = row0 >> 11;            // row0 / 2048
    const int t0 = (row0 & 2047) + r0;
#pragma unroll
    for (int jj = 0; jj < 4; ++jj) {
        const int j = j0 + jj;
        const float bX = bias[j];
        const float bY = bias[j + 64];
        const float sY = (j < 32) ? S2f : S1f;  // col j+64: g if <96 else o
        uint4 o;
        o.x = h2u(pkrtz((acc[0][jj] + bX) * S1f, (acc[0][jj + 4] + bY) * sY));
        o.y = h2u(pkrtz((acc[1][jj] + bX) * S1f, (acc[1][jj + 4] + bY) * sY));
        o.z = h2u(pkrtz((acc[2][jj] + bX) * S1f, (acc[2][jj + 4] + bY) * sY));
        o.w = h2u(pkrtz((acc[3][jj] + bX) * S1f, (acc[3][jj + 4] + bY) * sY));
        *(uint4*)(xg2 + (size_t)(b * 64 + j) * TT + t0) = o;
    }
}

// ---- Kernel 2: LSTM scan, TWO chains per wave, statement-interleaved ------
// Block bid handles batches 2*bid (A) and 2*bid+1 (B). Each chain uses the
// full round-8 structure (lane l owns gate cols l, l+64; h replicated across
// halves; all-VALU gather; permlane32 gate exchange). Every A statement is
// immediately followed by its B twin so the scheduler sees dependency
// distance 2 at every point — B's issue fills A's latency stalls and vice
// versa. Wh registers are shared between the chains.
__global__ __launch_bounds__(64) void lstm_rec(const unsigned* __restrict__ xg2,
                                               const float* __restrict__ Wh,
                                               const float* __restrict__ Wd,
                                               const float* __restrict__ bd,
                                               float* __restrict__ out) {
    const int l = threadIdx.x;  // 0..63
    const int m = l & 31;
    const bool lo = (l < HH);
    const int b0 = blockIdx.x * 2;

    // ---- discover gather permutation: run the tree on the index ----
    unsigned iv[16];
    gather_tree((unsigned)m, iv);

    // ---- load Wh columns l and l+64, permuted + prescaled + fp16-packed ---
    const float scx = S1f;                 // col l: i (lo) or f (hi) -> sigmoid
    const float scy = lo ? S2f : S1f;      // col l+64: g (lo, tanh) or o (hi)
    half2_t whx[16], why[16];
#pragma unroll
    for (int r = 0; r < 16; ++r) {
        const int p  = (int)(iv[r] & 31u);
        const int p2 = p ^ 1;
        whx[r] = pkrtz(Wh[p * GG + l] * scx,       Wh[p2 * GG + l] * scx);
        why[r] = pkrtz(Wh[p * GG + l + 64] * scy,  Wh[p2 * GG + l + 64] * scy);
    }

    // per-lane affine for act1: tanh = 2*s-1 (lo), sigmoid = s (hi)
    const float A1 = lo ? 2.f : 1.f;
    const float B1 = lo ? -1.f : 0.f;

    float hA = 0.f, cA = 0.f, hB = 0.f, cB = 0.f;

    const unsigned* pA = xg2 + (size_t)(b0 * 64 + l) * TT;
    const unsigned* pB = xg2 + (size_t)((b0 + 1) * 64 + l) * TT;

    uint4 curA = *(const uint4*)(pA);
    uint4 curB = *(const uint4*)(pB);
    uint4 nxtA = *(const uint4*)(pA + 4);
    uint4 nxtB = *(const uint4*)(pB + 4);

    auto dual_step = [&](unsigned wA, unsigned wB)
        __attribute__((always_inline)) {
        // ---- gather trees, interleaved ----
        unsigned hnA = DPP_(__float_as_uint(hA), CTRL_XOR1);
        unsigned hnB = DPP_(__float_as_uint(hB), CTRL_XOR1);
        unsigned g0A = h2u(pkrtz(hA, __uint_as_float(hnA)));
        unsigned g0B = h2u(pkrtz(hB, __uint_as_float(hnB)));
        unsigned gA[16], gB[16];
        unsigned v1A = DPP_(g0A, CTRL_XOR2);
        unsigned v1B = DPP_(g0B, CTRL_XOR2);
#if HAVE_PL16
        auto swA = __builtin_amdgcn_permlane16_swap(g0A, v1A, false, false);
        auto swB = __builtin_amdgcn_permlane16_swap(g0B, v1B, false, false);
        gA[0] = (unsigned)swA[0];
        gB[0] = (unsigned)swB[0];
        gA[1] = (unsigned)swA[1];
        gB[1] = (unsigned)swB[1];
        gA[2] = DPP_(gA[0], CTRL_XOR2);
        gB[2] = DPP_(gB[0], CTRL_XOR2);
        gA[3] = DPP_(gA[1], CTRL_XOR2);
        gB[3] = DPP_(gB[1], CTRL_XOR2);
#else
        gA[0] = g0A;            gB[0] = g0B;
        gA[1] = v1A;            gB[1] = v1B;
        gA[2] = SWZ16_(g0A);    gB[2] = SWZ16_(g0B);
        gA[3] = SWZ16_(v1A);    gB[3] = SWZ16_(v1B);
#endif
#pragma unroll
        for (int r = 0; r < 4; ++r) {
            gA[4 + r] = DPP_(gA[r], CTRL_ROR4);
            gB[4 + r] = DPP_(gB[r], CTRL_ROR4);
        }
#pragma unroll
        for (int r = 0; r < 8; ++r) {
            gA[8 + r] = DPP_(gA[r], CTRL_ROR8);
            gB[8 + r] = DPP_(gB[r], CTRL_ROR8);
        }

        // ---- matvecs, interleaved (shared weights) ----
        half2_t xvA = u2h(wA);
        half2_t xvB = u2h(wB);
        float axA[4] = {(float)xvA[0], 0.f, 0.f, 0.f};
        float axB[4] = {(float)xvB[0], 0.f, 0.f, 0.f};
        float ayA[4] = {(float)xvA[1], 0.f, 0.f, 0.f};
        float ayB[4] = {(float)xvB[1], 0.f, 0.f, 0.f};
#pragma unroll
        for (int r = 0; r < 16; ++r) {
            half2_t hpA = u2h(gA[r]);
            half2_t hpB = u2h(gB[r]);
            axA[r & 3] = fdot2_(hpA, whx[r], axA[r & 3]);
            axB[r & 3] = fdot2_(hpB, whx[r], axB[r & 3]);
            ayA[r & 3] = fdot2_(hpA, why[r], ayA[r & 3]);
            ayB[r & 3] = fdot2_(hpB, why[r], ayB[r & 3]);
        }
        float a0A = (axA[0] + axA[1]) + (axA[2] + axA[3]);
        float a0B = (axB[0] + axB[1]) + (axB[2] + axB[3]);
        float a1A = (ayA[0] + ayA[1]) + (ayA[2] + ayA[3]);
        float a1B = (ayB[0] + ayB[1]) + (ayB[2] + ayB[3]);

        // ---- activations, interleaved ----
        float e0A = exp2_(a0A);
        float e0B = exp2_(a0B);
        float e1A = exp2_(a1A);
        float e1B = exp2_(a1B);
        float act0A = rcp_(1.f + e0A);
        float act0B = rcp_(1.f + e0B);
        float s1A = rcp_(1.f + e1A);
        float s1B = rcp_(1.f + e1B);
        float act1A = fmaf(A1, s1A, B1);
        float act1B = fmaf(A1, s1B, B1);

        // ---- gate exchange, interleaved ----
        auto pqA = __builtin_amdgcn_permlane32_swap(__float_as_uint(act0A),
                                                    __float_as_uint(act1A), false, false);
        auto pqB = __builtin_amdgcn_permlane32_swap(__float_as_uint(act0B),
                                                    __float_as_uint(act1B), false, false);
        auto uvA = __builtin_amdgcn_permlane32_swap(__float_as_uint(act1A),
                                                    __float_as_uint(act0A), false, false);
        auto uvB = __builtin_amdgcn_permlane32_swap(__float_as_uint(act1B),
                                                    __float_as_uint(act0B), false, false);
        float pA_ = __uint_as_float(pqA[0]);
        float pB_ = __uint_as_float(pqB[0]);
        float qA_ = __uint_as_float(pqA[1]);
        float qB_ = __uint_as_float(pqB[1]);
        float uA_ = __uint_as_float(uvA[0]);
        float uB_ = __uint_as_float(uvB[0]);
        float vA_ = __uint_as_float(uvA[1]);
        float vB_ = __uint_as_float(uvB[1]);

        float fA = lo ? qA_ : act0A;
        float fB = lo ? qB_ : act0B;
        float oA = lo ? vA_ : act1A;
        float oB = lo ? vB_ : act1B;
        float igA = uA_ * pA_;
        float igB = uB_ * pB_;
        cA = fmaf(fA, cA, igA);
        cB = fmaf(fB, cB, igB);
        float ecA = exp2_(cA * S2f);
        float ecB = exp2_(cB * S2f);
        float rcA = rcp_(1.f + ecA);
        float rcB = rcp_(1.f + ecB);
        float tcA = fmaf(2.f, rcA, -1.f);
        float tcB = fmaf(2.f, rcB, -1.f);
        hA = oA * tcA;
        hB = oB * tcB;
    };

#pragma unroll 1
    for (int t4 = 0; t4 < TT; t4 += 4) {
        uint4 uA = curA, uB = curB;
        curA = nxtA; curB = nxtB;
        if (t4 + 8 < TT) {
            nxtA = *(const uint4*)(pA + t4 + 8);
            nxtB = *(const uint4*)(pB + t4 + 8);
        }
        dual_step(uA.x, uB.x);
        dual_step(uA.y, uB.y);
        dual_step(uA.z, uB.z);
        dual_step(uA.w, uB.w);
    }

    // out[b] = h_T @ Wd + bd   (each h[k] appears twice across 64 lanes)
    const float wd = Wd[m];
    float ca = hA * wd;
    float cb = hB * wd;
#pragma unroll
    for (int off = 32; off >= 1; off >>= 1) {
        ca += __shfl_xor(ca, off, 64);
        cb += __shfl_xor(cb, off, 64);
    }
    if (l == 0) {
        out[b0]     = fmaf(0.5f, ca, bd[0]);
        out[b0 + 1] = fmaf(0.5f, cb, bd[0]);
    }
}

extern "C" void kernel_launch(void* const* d_in, const int* in_sizes, int n_in,
                              void* d_out, int out_size, void* d_ws, size_t ws_size,
                              hipStream_t stream) {
    const float* X    = (const float*)d_in[0];
    const float* Wx   = (const float*)d_in[1];
    const float* Wh   = (const float*)d_in[2];
    const float* bias = (const float*)d_in[3];
    const float* Wd   = (const float*)d_in[4];
    const float* bd   = (const float*)d_in[5];
    float* out = (float*)d_out;
    unsigned* xg2 = (unsigned*)d_ws;  // [64][64][2048] half2-pairs = 32 MB

    hipLaunchKernelGGL(xg_gemm, dim3((BB * TT) / 64), dim3(256), 0, stream,
                       X, Wx, bias, xg2);
    hipLaunchKernelGGL(lstm_rec, dim3(BB / 2), dim3(64), 0, stream,
                       xg2, Wh, Wd, bd, out);
}

// Round 13
// 454.066 us; speedup vs baseline: 1.7418x; 1.7418x over previous
//
#include <hip/hip_runtime.h>
#include <math.h>

#define BB 64
#define TT 2048
#define FF 128
#define HH 32
#define GG 128  // 4*H

// gate-column prescale: sigma(a) = rcp(1 + exp2(S1*a)), tanh(a) = 2*rcp(1+exp2(S2*a))-1
#define S1f (-1.4426950408889634f)  // -log2(e)
#define S2f (-2.8853900817779268f)  // -2*log2(e)

typedef _Float16 half2_t __attribute__((ext_vector_type(2)));

__device__ __forceinline__ unsigned h2u(half2_t v) {
    unsigned u; __builtin_memcpy(&u, &v, 4); return u;
}
__device__ __forceinline__ half2_t u2h(unsigned u) {
    half2_t v; __builtin_memcpy(&v, &u, 4); return v;
}
__device__ __forceinline__ half2_t pkrtz(float a, float b) {
    auto r = __builtin_amdgcn_cvt_pkrtz(a, b);  // __fp16 vec2, same bits
    half2_t v; __builtin_memcpy(&v, &r, 4); return v;
}
__device__ __forceinline__ float rcp_(float x) { return __builtin_amdgcn_rcpf(x); }
__device__ __forceinline__ float exp2_(float x) { return __builtin_amdgcn_exp2f(x); }
__device__ __forceinline__ float fdot2_(half2_t a, half2_t b, float c) {
    return __builtin_amdgcn_fdot2(a, b, c, false);
}

// DPP lane shuffles (within rows of 16 / quads); bound_ctrl=1, all rows/banks
#define DPP_(x, ctrl) \
    ((unsigned)__builtin_amdgcn_mov_dpp((int)(x), (ctrl), 0xF, 0xF, true))
#define CTRL_XOR1 0xB1  // quad_perm [1,0,3,2]
#define CTRL_XOR2 0x4E  // quad_perm [2,3,0,1]
// ds_swizzle bit-mode xor16 within 32-lane groups: (16<<10)|0x1F
#define SWZ16_(x) ((unsigned)__builtin_amdgcn_ds_swizzle((int)(x), 0x401F))

#if __has_builtin(__builtin_amdgcn_permlane16_swap)
#define HAVE_PL16 1
#else
#define HAVE_PL16 0
#endif

// 16-reg all-gather: seed v0 = per-lane pair (or index for discovery).
// Depth-5 tree: s0/s1 hold opposite-row pairs at every lane; row-local
// ror2..14 cover all 8 pair-slots of each row -> full 32-value coverage.
// Discovery (running the identical ops on the lane index) makes the exact
// permutation irrelevant to correctness; only coverage matters.
__device__ __forceinline__ void gather_tree(unsigned v0, unsigned g[16]) {
#if HAVE_PL16
    unsigned v1 = DPP_(v0, CTRL_XOR2);
    auto sw = __builtin_amdgcn_permlane16_swap(v0, v1, false, false);
    unsigned s0 = (unsigned)sw[0], s1 = (unsigned)sw[1];
#else
    unsigned s0 = v0;
    unsigned s1 = SWZ16_(v0);   // other 16-row within the 32-group
#endif
    g[0] = s0;                 g[1] = s1;
    g[2]  = DPP_(s0, 0x122);   g[3]  = DPP_(s1, 0x122);   // row_ror:2
    g[4]  = DPP_(s0, 0x124);   g[5]  = DPP_(s1, 0x124);   // row_ror:4
    g[6]  = DPP_(s0, 0x126);   g[7]  = DPP_(s1, 0x126);   // row_ror:6
    g[8]  = DPP_(s0, 0x128);   g[9]  = DPP_(s1, 0x128);   // row_ror:8
    g[10] = DPP_(s0, 0x12A);   g[11] = DPP_(s1, 0x12A);   // row_ror:10
    g[12] = DPP_(s0, 0x12C);   g[13] = DPP_(s1, 0x12C);   // row_ror:12
    g[14] = DPP_(s0, 0x12E);   g[15] = DPP_(s1, 0x12E);   // row_ror:14
}

// ---- Kernel 1: xg2[b][j][t] = half2( S*(X@Wx+b)[col j], S*(X@Wx+b)[col j+64] )
// fp16-fdot2 inner loop: X and Wx staged as packed K-pairs in LDS.
__global__ __launch_bounds__(256) void xg_gemm(const float* __restrict__ X,
                                               const float* __restrict__ Wx,
                                               const float* __restrict__ bias,
                                               unsigned* __restrict__ xg2) {
    __shared__ unsigned XLh[64][16];    // [row][q]  : half2(X[.,f0+2q], X[.,f0+2q+1])  4 KB
    __shared__ unsigned WLh[16][128];   // [q][col]  : half2(Wx[f0+2q][c], Wx[f0+2q+1][c]) 8 KB
    const int tid = threadIdx.x;
    const int row0 = blockIdx.x * 64;   // flattened b*T + t0 (one b per block)
    const int j0 = (tid & 15) * 4;   // 4 X-cols (j0..j0+3) + 4 Y-cols (+64)
    const int r0 = (tid >> 4) * 4;   // 4 output rows (consecutive t)

    float acc[4][8];                 // [row][4 X + 4 Y]
#pragma unroll
    for (int r = 0; r < 4; ++r)
#pragma unroll
        for (int jj = 0; jj < 8; ++jj) acc[r][jj] = 0.f;

    for (int f0 = 0; f0 < FF; f0 += 32) {
        __syncthreads();
        // stage Wx K-pairs: thread -> (q, jq): q = tid>>5 and q+8; j = (tid&31)*4
        {
            const int jq = (tid & 31) * 4;
#pragma unroll
            for (int qq = 0; qq < 2; ++qq) {
                const int q = (tid >> 5) + qq * 8;
                float4 wa = *(const float4*)(Wx + (size_t)(f0 + 2 * q) * GG + jq);
                float4 wb = *(const float4*)(Wx + (size_t)(f0 + 2 * q + 1) * GG + jq);
                WLh[q][jq + 0] = h2u(pkrtz(wa.x, wb.x));
                WLh[q][jq + 1] = h2u(pkrtz(wa.y, wb.y));
                WLh[q][jq + 2] = h2u(pkrtz(wa.z, wb.z));
                WLh[q][jq + 3] = h2u(pkrtz(wa.w, wb.w));
            }
        }
        // stage X K-pairs: as round 8 but packed (2 half2 per float4)
        {
            int lin = tid * 4;
            int row = lin >> 5, fi = lin & 31;
            float4 x = *(const float4*)(X + (size_t)(row0 + row) * FF + f0 + fi);
            XLh[row][(fi >> 1) + 0] = h2u(pkrtz(x.x, x.y));
            XLh[row][(fi >> 1) + 1] = h2u(pkrtz(x.z, x.w));
            lin = (tid + 256) * 4;
            row = lin >> 5; fi = lin & 31;
            x = *(const float4*)(X + (size_t)(row0 + row) * FF + f0 + fi);
            XLh[row][(fi >> 1) + 0] = h2u(pkrtz(x.x, x.y));
            XLh[row][(fi >> 1) + 1] = h2u(pkrtz(x.z, x.w));
        }
        __syncthreads();
#pragma unroll 4
        for (int q = 0; q < 16; ++q) {
            half2_t xv[4];
#pragma unroll
            for (int r = 0; r < 4; ++r) xv[r] = u2h(XLh[r0 + r][q]);
            uint4 w0 = *(uint4*)&WLh[q][j0];        // X cols j0..j0+3
            uint4 w1 = *(uint4*)&WLh[q][j0 + 64];   // Y cols j0+64..j0+67
            unsigned wj[8] = {w0.x, w0.y, w0.z, w0.w, w1.x, w1.y, w1.z, w1.w};
#pragma unroll
            for (int r = 0; r < 4; ++r)
#pragma unroll
                for (int jj = 0; jj < 8; ++jj)
                    acc[r][jj] = fdot2_(xv[r], u2h(wj[jj]), acc[r][jj]);
        }
    }
    const int b  = row0 >> 11;            // row0 / 2048
    const int t0 = (row0 & 2047) + r0;
#pragma unroll
    for (int jj = 0; jj < 4; ++jj) {
        const int j = j0 + jj;
        const float bX = bias[j];
        const float bY = bias[j + 64];
        const float sY = (j < 32) ? S2f : S1f;  // col j+64: g if <96 else o
        uint4 o;
        o.x = h2u(pkrtz((acc[0][jj] + bX) * S1f, (acc[0][jj + 4] + bY) * sY));
        o.y = h2u(pkrtz((acc[1][jj] + bX) * S1f, (acc[1][jj + 4] + bY) * sY));
        o.z = h2u(pkrtz((acc[2][jj] + bX) * S1f, (acc[2][jj + 4] + bY) * sY));
        o.w = h2u(pkrtz((acc[3][jj] + bX) * S1f, (acc[3][jj + 4] + bY) * sY));
        *(uint4*)(xg2 + (size_t)(b * 64 + j) * TT + t0) = o;
    }
}

// ---- Kernel 2: single-wave LSTM scan (round-8 structure, shortened path) --
// One block (one wave) per batch element. Lane l owns gate columns l, l+64;
// h[l&31], c[l&31] replicated across halves. Depth-5 all-VALU gather;
// select-free gate broadcast via permlane32_swap(x,x).
__global__ __launch_bounds__(64) void lstm_rec(const unsigned* __restrict__ xg2,
                                               const float* __restrict__ Wh,
                                               const float* __restrict__ Wd,
                                               const float* __restrict__ bd,
                                               float* __restrict__ out) {
    const int l = threadIdx.x;  // 0..63
    const int m = l & 31;
    const bool lo = (l < HH);
    const int b = blockIdx.x;

    // ---- discover gather permutation: run the tree on the index ----
    unsigned iv[16];
    gather_tree((unsigned)m, iv);

    // ---- load Wh columns l and l+64, permuted + prescaled + fp16-packed ---
    const float scx = S1f;                 // col l: i (lo) or f (hi) -> sigmoid
    const float scy = lo ? S2f : S1f;      // col l+64: g (lo, tanh) or o (hi)
    half2_t whx[16], why[16];
#pragma unroll
    for (int r = 0; r < 16; ++r) {
        const int p  = (int)(iv[r] & 31u);
        const int p2 = p ^ 1;
        whx[r] = pkrtz(Wh[p * GG + l] * scx,       Wh[p2 * GG + l] * scx);
        why[r] = pkrtz(Wh[p * GG + l + 64] * scy,  Wh[p2 * GG + l + 64] * scy);
    }

    // per-lane affine for act1: tanh = 2*s-1 (lo), sigmoid = s (hi)
    const float A1 = lo ? 2.f : 1.f;
    const float B1 = lo ? -1.f : 0.f;

    float h = 0.f;  // lane l: h[m]
    float c = 0.f;  // lane l: c[m]

    const unsigned* pX = xg2 + (size_t)(b * 64 + l) * TT;

    uint4 cur = *(const uint4*)(pX);
    uint4 nxt = *(const uint4*)(pX + 4);

    auto step = [&](unsigned w) __attribute__((always_inline)) {
        half2_t xv = u2h(w);
        float xi = (float)xv[0];   // prescaled preact, col l   (i|f)
        float xy = (float)xv[1];   // prescaled preact, col l+64 (g|o)
        // all-VALU butterfly gather: h -> 16 packed half2 (depth 5)
        unsigned hn = DPP_(__float_as_uint(h), CTRL_XOR1);
        unsigned g0 = h2u(pkrtz(h, __uint_as_float(hn)));
        unsigned g[16];
        gather_tree(g0, g);
        // matvec: 32 all-VGPR fdot2, 4-way split accumulators
        float ax[4] = {xi, 0.f, 0.f, 0.f};
        float ay[4] = {xy, 0.f, 0.f, 0.f};
#pragma unroll
        for (int r = 0; r < 16; ++r) {
            half2_t hp = u2h(g[r]);
            ax[r & 3] = fdot2_(hp, whx[r], ax[r & 3]);
            ay[r & 3] = fdot2_(hp, why[r], ay[r & 3]);
        }
        float a0 = (ax[0] + ax[1]) + (ax[2] + ax[3]);
        float a1 = (ay[0] + ay[1]) + (ay[2] + ay[3]);
        // act0 = sigmoid (i|f); act1 = tanh (g) on lo, sigmoid (o) on hi
        float act0 = rcp_(1.f + exp2_(a0));
        float act1 = fmaf(A1, rcp_(1.f + exp2_(a1)), B1);
        // select-free gate broadcast: swap(x,x) duplicates each half to both
        auto sw0 = __builtin_amdgcn_permlane32_swap(__float_as_uint(act0),
                                                    __float_as_uint(act0), false, false);
        auto sw1 = __builtin_amdgcn_permlane32_swap(__float_as_uint(act1),
                                                    __float_as_uint(act1), false, false);
        float i_all = __uint_as_float(sw0[0]);
        float f_all = __uint_as_float(sw0[1]);
        float g_all = __uint_as_float(sw1[0]);
        float o_all = __uint_as_float(sw1[1]);
        c = fmaf(f_all, c, i_all * g_all);
        float tc = fmaf(2.f, rcp_(1.f + exp2_(c * S2f)), -1.f);  // tanh(c)
        h = o_all * tc;
    };

#pragma unroll 1
    for (int t4 = 0; t4 < TT; t4 += 4) {
        uint4 u = cur;
        cur = nxt;
        if (t4 + 8 < TT) nxt = *(const uint4*)(pX + t4 + 8);
        step(u.x);
        step(u.y);
        step(u.z);
        step(u.w);
    }

    // out[b] = h_T @ Wd + bd   (each h[k] appears twice across 64 lanes)
    float contrib = h * Wd[m];
#pragma unroll
    for (int off = 32; off >= 1; off >>= 1)
        contrib += __shfl_xor(contrib, off, 64);
    if (l == 0) out[b] = fmaf(0.5f, contrib, bd[0]);
}

extern "C" void kernel_launch(void* const* d_in, const int* in_sizes, int n_in,
                              void* d_out, int out_size, void* d_ws, size_t ws_size,
                              hipStream_t stream) {
    const float* X    = (const float*)d_in[0];
    const float* Wx   = (const float*)d_in[1];
    const float* Wh   = (const float*)d_in[2];
    const float* bias = (const float*)d_in[3];
    const float* Wd   = (const float*)d_in[4];
    const float* bd   = (const float*)d_in[5];
    float* out = (float*)d_out;
    unsigned* xg2 = (unsigned*)d_ws;  // [64][64][2048] half2-pairs = 32 MB

    hipLaunchKernelGGL(xg_gemm, dim3((BB * TT) / 64), dim3(256), 0, stream,
                       X, Wx, bias, xg2);
    hipLaunchKernelGGL(lstm_rec, dim3(BB), dim3(64), 0, stream,
                       xg2, Wh, Wd, bd, out);
}